// Round 7
// baseline (737.668 us; speedup 1.0000x reference)
//
#include <hip/hip_runtime.h>
#include <stdint.h>

// Problem constants
#define DIM    1024
#define RANK   16
#define M_TOT  8192          // 2*4096 rows of x
#define N_TOT  3072          // 3*DIM output features
#define K_TOT  1024

// GEMM tiling: block = 256x256, BK=32, 8 waves (2M x 4N), wave tile 128x64
#define BM 256
#define BN 256
#define BK 32
#define NT (K_TOT / BK)      // 32 K-tiles
// LDS ring: 2 slots x 32 KB (A 16 KB + B 16 KB) = 64 KB -> 2 blocks/CU
#define SLOT_H   16384       // halves per slot
#define SLOT_V   2048        // s8v per slot
#define B_OFF_H  8192        // B region offset (halves)
#define B_OFF_V  1024        // B region offset (s8v)

typedef __attribute__((ext_vector_type(8))) short  s8v;   // 8 x bf16 (raw bits)
typedef __attribute__((ext_vector_type(4))) float  f4v;   // MFMA acc

__device__ __forceinline__ unsigned short f2bf(float f) {
    union { float f; unsigned int u; } v; v.f = f;
    unsigned int u = v.u;
    u += 0x7FFFu + ((u >> 16) & 1u);   // round-to-nearest-even
    return (unsigned short)(u >> 16);
}

// Async global->LDS DMA, 16 B/lane. LDS dest is wave-uniform base + lane*16;
// global src carries the fragment swizzle (m173 pattern).
__device__ __forceinline__ void gload_lds16(const unsigned short* g,
                                            unsigned short* l) {
    __builtin_amdgcn_global_load_lds(
        (const __attribute__((address_space(1))) void*)g,
        (__attribute__((address_space(3))) void*)l,
        16, 0, 0);
}

// ---------------- Kernel 1: fused prep (unchanged from round 3) ----------------
__global__ __launch_bounds__(256)
void prep(const float4* __restrict__ x, ushort4* __restrict__ xb,
          const float* __restrict__ W,
          const float* __restrict__ Aq, const float* __restrict__ Bq,
          const float* __restrict__ Ak, const float* __restrict__ Bk,
          const float* __restrict__ Av, const float* __restrict__ Bv,
          const float* __restrict__ alpha_p,
          unsigned short* __restrict__ Wb) {
    const int tid = threadIdx.x;
    if (blockIdx.x < 2048) {
        int i = blockIdx.x * 256 + tid;          // 2048*256*4 = 2097152 exact
        #pragma unroll
        for (int k = 0; k < 4; ++k) {
            float4 v = x[i];
            ushort4 o;
            o.x = f2bf(v.x); o.y = f2bf(v.y); o.z = f2bf(v.z); o.w = f2bf(v.w);
            xb[i] = o;
            i += 2048 * 256;
        }
    } else {
        const int bid2 = blockIdx.x - 2048;      // 0..191
        const int sel  = bid2 >> 6;              // 0=q 1=k 2=v
        const int rb   = bid2 & 63;              // rows rb*16..+16
        const float* Am = (sel == 0) ? Aq : (sel == 1) ? Ak : Av;  // [RANK, DIM]
        const float* Bm = (sel == 0) ? Bq : (sel == 1) ? Bk : Bv;  // [DIM, RANK]

        __shared__ float sb[16][RANK];
        {
            const int row = rb * 16 + (tid >> 4);
            sb[tid >> 4][tid & 15] = alpha_p[0] * Bm[row * RANK + (tid & 15)];
        }
        __syncthreads();

        float4 a4[RANK];                          // A column-slice, 64 VGPRs
        #pragma unroll
        for (int r = 0; r < RANK; ++r)
            a4[r] = ((const float4*)(Am + r * DIM))[tid];

        #pragma unroll
        for (int row = 0; row < 16; ++row) {
            const int o = sel * 1024 + rb * 16 + row;
            float4 w = ((const float4*)(W + (size_t)o * DIM))[tid];
            #pragma unroll
            for (int r = 0; r < RANK; ++r) {
                const float s = sb[row][r];
                w.x += s * a4[r].x; w.y += s * a4[r].y;
                w.z += s * a4[r].z; w.w += s * a4[r].w;
            }
            ushort4 ov;
            ov.x = f2bf(w.x); ov.y = f2bf(w.y); ov.z = f2bf(w.z); ov.w = f2bf(w.w);
            ((ushort4*)(Wb + (size_t)o * DIM))[tid] = ov;
        }
    }
}

// ---------------- Kernel 2: bf16 MFMA GEMM, C = Xb * Wb^T + bias ----------------
// Ring-2 + 2 blocks/CU co-residency (the m97/m114 mechanism):
//   64 KB LDS + <=128 VGPR -> 2 blocks (16 waves) per CU; all 384 blocks
//   resident from t=0 (no 1.5-round dispatch tail, r6's -25%), and each CU's
//   two INDEPENDENT blocks mutually hide barrier/vmcnt/LDS-burst stalls --
//   rounds 1-6 all ran 1 block/CU and paid the serialization in full.
// Per quad q (steady state, per wave):
//   1. STAGE(q+1) -> slot (q+1)&1  [freed by the barrier ending quad q-1]
//   2. vmcnt(4): tile q's 4 loads landed; q+1's stay in flight (T4: counted)
//   3. s_barrier: tile q published across waves
//   4. COMPUTE(q): 12 ds_read_b128 + 32 MFMA (setprio-wrapped)
//   5. s_barrier: reads of slot q&1 done (next quad's STAGE may overwrite)
__global__ __launch_bounds__(512, 4)
void gemm_bt(const unsigned short* __restrict__ Xb,
             const unsigned short* __restrict__ Wb,
             const float* __restrict__ bias,
             float* __restrict__ out) {
    __shared__ __align__(16) unsigned short S[2 * SLOT_H];   // 64 KB ring

    const int tid  = threadIdx.x;
    const int wave = tid >> 6;       // 0..7
    const int lane = tid & 63;
    const int l15  = lane & 15;
    const int lq   = lane >> 4;      // 0..3
    const int wr   = wave >> 2;      // M half    0..1 (128 rows)
    const int wc   = wave & 3;       // N quarter 0..3 (64 cols)

    // XCD map (r5/r6-proven): per XCD a 4bm x 12bn chunk; A-stripe (2 MB)
    // L2-resident, B streams via L3. Bijective for 384 = 8 x 48.
    const int bid = blockIdx.x;
    const int xcd = bid & 7;
    const int s   = bid >> 3;        // 0..47
    const int bm  = xcd * 4 + s / 12;
    const int bn  = s % 12;

    // Staging: per K-tile, A = 16 chunks of 1 KB (16 rows x 32 k), B = 16.
    // Wave w owns A chunks {2w, 2w+1} and B chunks {2w, 2w+1} -> 4 loads/quad.
    // Chunk c: rows c*16 + l15, k-cols lq*8 (8 halves/lane). LDS chunk c =
    // wave-uniform base + lane*16B (linear DMA order, verified rounds 0-6).
    const unsigned short* aptr[2];
    const unsigned short* bptr[2];
    int aoff[2], boff[2];            // chunk bases (halves) within a slot
    #pragma unroll
    for (int u = 0; u < 2; ++u) {
        const int c   = wave * 2 + u;            // 0..15
        const int row = c * 16 + l15;            // 0..255
        const int col = lq << 3;                 // 0..24
        aptr[u] = Xb + (size_t)(bm * BM + row) * K_TOT + col;
        bptr[u] = Wb + (size_t)(bn * BN + row) * K_TOT + col;
        aoff[u] = c * 512;
        boff[u] = B_OFF_H + c * 512;
    }

    #define STAGE(q)                                                         \
    {                                                                        \
        unsigned short* sl = &S[((q) & 1) * SLOT_H];                         \
        const int kk = (q) * BK;                                             \
        gload_lds16(aptr[0] + kk, sl + aoff[0]);                             \
        gload_lds16(aptr[1] + kk, sl + aoff[1]);                             \
        gload_lds16(bptr[0] + kk, sl + boff[0]);                             \
        gload_lds16(bptr[1] + kk, sl + boff[1]);                             \
    }

    f4v acc[8][4] = {};

    #define COMPUTE(q)                                                       \
    {                                                                        \
        const s8v* P = (const s8v*)S + ((q) & 1) * SLOT_V;                   \
        s8v af[8], bf[4];                                                    \
        _Pragma("unroll")                                                    \
        for (int j = 0; j < 4; ++j)                                          \
            bf[j] = P[B_OFF_V + (wc * 4 + j) * 64 + lane];                   \
        _Pragma("unroll")                                                    \
        for (int i = 0; i < 8; ++i)                                          \
            af[i] = P[(wr * 8 + i) * 64 + lane];                             \
        __builtin_amdgcn_s_setprio(1);                                       \
        _Pragma("unroll")                                                    \
        for (int i = 0; i < 8; ++i)                                          \
            _Pragma("unroll")                                                \
            for (int j = 0; j < 4; ++j)                                      \
                acc[i][j] = __builtin_amdgcn_mfma_f32_16x16x32_bf16(         \
                    af[i], bf[j], acc[i][j], 0, 0, 0);                       \
        __builtin_amdgcn_s_setprio(0);                                       \
    }

    // Publish sync: counted vmcnt + barrier, fence-sandwiched (r6 discipline).
    #define PUBSYNC(n)                                                       \
    {                                                                        \
        __builtin_amdgcn_sched_barrier(0);                                   \
        asm volatile("s_waitcnt vmcnt(" #n ")" ::: "memory");                \
        __builtin_amdgcn_s_barrier();                                        \
        __builtin_amdgcn_sched_barrier(0);                                   \
    }
    // Read-done sync: reads of the just-used slot complete before next STAGE.
    #define ENDSYNC()                                                        \
    {                                                                        \
        __builtin_amdgcn_sched_barrier(0);                                   \
        __builtin_amdgcn_s_barrier();                                        \
        __builtin_amdgcn_sched_barrier(0);                                   \
    }

    // Prologue: tile 0 in flight.
    STAGE(0);

    #pragma unroll 2
    for (int q = 0; q < NT; ++q) {
        if (q + 1 < NT) {
            STAGE(q + 1);      // slot (q+1)&1, freed by the ENDSYNC of q-1
            PUBSYNC(4);        // tile q landed; q+1's 4 loads stay in flight
        } else {
            PUBSYNC(0);        // last tile: drain
        }
        COMPUTE(q);
        if (q + 1 < NT) ENDSYNC();   // slot q&1 reads done; STAGE(q+2) may clobber
    }
    #undef STAGE
    #undef COMPUTE
    #undef PUBSYNC
    #undef ENDSYNC

    // Epilogue: C/D layout col = lane&15, row = (lane>>4)*4 + reg  [m89]
    const int col_base = bn * BN + wc * 64;
    const int row_base = bm * BM + wr * 128 + lq * 4;
    #pragma unroll
    for (int j = 0; j < 4; ++j) {
        const int col = col_base + j * 16 + l15;
        const float bv = bias[col];
        #pragma unroll
        for (int i = 0; i < 8; ++i) {
            const int row = row_base + i * 16;
            #pragma unroll
            for (int r = 0; r < 4; ++r)
                out[(size_t)(row + r) * N_TOT + col] = acc[i][j][r] + bv;
        }
    }
}

extern "C" void kernel_launch(void* const* d_in, const int* in_sizes, int n_in,
                              void* d_out, int out_size, void* d_ws, size_t ws_size,
                              hipStream_t stream) {
    const float* x     = (const float*)d_in[0];   // [2,4096,1024]
    const float* W     = (const float*)d_in[1];   // [3072,1024]
    const float* b     = (const float*)d_in[2];   // [3072]
    const float* Aq    = (const float*)d_in[3];
    const float* Bq    = (const float*)d_in[4];
    const float* Ak    = (const float*)d_in[5];
    const float* Bk    = (const float*)d_in[6];
    const float* Av    = (const float*)d_in[7];
    const float* Bv    = (const float*)d_in[8];
    const float* alpha = (const float*)d_in[9];
    float* out = (float*)d_out;

    unsigned short* xb = (unsigned short*)d_ws;                                      // 16 MB
    unsigned short* Wb = (unsigned short*)((char*)d_ws + (size_t)M_TOT * K_TOT * 2); // +6 MB

    prep<<<2048 + 192, 256, 0, stream>>>((const float4*)x, (ushort4*)xb,
                                         W, Aq, Bq, Ak, Bk, Av, Bv, alpha, Wb);

    // 32 M-tiles x 12 N-tiles = 384 blocks, ALL co-resident (2 blocks/CU)
    gemm_bt<<<(M_TOT / BM) * (N_TOT / BN), 512, 0, stream>>>(xb, Wb, b, out);
}

// Round 8
// 239.932 us; speedup vs baseline: 3.0745x; 3.0745x over previous
//
#include <hip/hip_runtime.h>
#include <stdint.h>

// Problem constants
#define DIM    1024
#define RANK   16
#define M_TOT  8192          // 2*4096 rows of x
#define N_TOT  3072          // 3*DIM output features
#define K_TOT  1024

// GEMM tiling: block = 128x128, BK=32, 4 waves (2M x 2N), wave tile 64x64.
// Small block + small LDS + <=128 regs/wave -> 4 co-resident blocks/CU.
// Session law: global_load_lds fill rate ~= 7-9 B/cyc per BLOCK (r5,r6,m97);
// co-residency is the only lever that scaled it (m97: 21-22 B/cyc at 3/CU).
#define BM 128
#define BN 128
#define BK 32
#define NT (K_TOT / BK)      // 32 K-tiles
#define SLOT_H 8192          // halves per ring slot (A 8KB + B 8KB = 16KB)
#define SLOT_V 1024          // s8v per slot
#define B_OFF_V 512          // B region offset within slot (s8v)

typedef __attribute__((ext_vector_type(8))) short  s8v;   // 8 x bf16 (raw bits)
typedef __attribute__((ext_vector_type(4))) float  f4v;   // MFMA acc

__device__ __forceinline__ unsigned short f2bf(float f) {
    union { float f; unsigned int u; } v; v.f = f;
    unsigned int u = v.u;
    u += 0x7FFFu + ((u >> 16) & 1u);   // round-to-nearest-even
    return (unsigned short)(u >> 16);
}

// Async global->LDS DMA, 16 B/lane. LDS dest is wave-uniform base + lane*16;
// global src carries the fragment swizzle (m173 pattern).
__device__ __forceinline__ void gload_lds16(const unsigned short* g,
                                            unsigned short* l) {
    __builtin_amdgcn_global_load_lds(
        (const __attribute__((address_space(1))) void*)g,
        (__attribute__((address_space(3))) void*)l,
        16, 0, 0);
}

// ---------------- Kernel 1: fused prep (unchanged from round 3) ----------------
__global__ __launch_bounds__(256)
void prep(const float4* __restrict__ x, ushort4* __restrict__ xb,
          const float* __restrict__ W,
          const float* __restrict__ Aq, const float* __restrict__ Bq,
          const float* __restrict__ Ak, const float* __restrict__ Bk,
          const float* __restrict__ Av, const float* __restrict__ Bv,
          const float* __restrict__ alpha_p,
          unsigned short* __restrict__ Wb) {
    const int tid = threadIdx.x;
    if (blockIdx.x < 2048) {
        int i = blockIdx.x * 256 + tid;          // 2048*256*4 = 2097152 exact
        #pragma unroll
        for (int k = 0; k < 4; ++k) {
            float4 v = x[i];
            ushort4 o;
            o.x = f2bf(v.x); o.y = f2bf(v.y); o.z = f2bf(v.z); o.w = f2bf(v.w);
            xb[i] = o;
            i += 2048 * 256;
        }
    } else {
        const int bid2 = blockIdx.x - 2048;      // 0..191
        const int sel  = bid2 >> 6;              // 0=q 1=k 2=v
        const int rb   = bid2 & 63;              // rows rb*16..+16
        const float* Am = (sel == 0) ? Aq : (sel == 1) ? Ak : Av;  // [RANK, DIM]
        const float* Bm = (sel == 0) ? Bq : (sel == 1) ? Bk : Bv;  // [DIM, RANK]

        __shared__ float sb[16][RANK];
        {
            const int row = rb * 16 + (tid >> 4);
            sb[tid >> 4][tid & 15] = alpha_p[0] * Bm[row * RANK + (tid & 15)];
        }
        __syncthreads();

        float4 a4[RANK];                          // A column-slice, 64 VGPRs
        #pragma unroll
        for (int r = 0; r < RANK; ++r)
            a4[r] = ((const float4*)(Am + r * DIM))[tid];

        #pragma unroll
        for (int row = 0; row < 16; ++row) {
            const int o = sel * 1024 + rb * 16 + row;
            float4 w = ((const float4*)(W + (size_t)o * DIM))[tid];
            #pragma unroll
            for (int r = 0; r < RANK; ++r) {
                const float s = sb[row][r];
                w.x += s * a4[r].x; w.y += s * a4[r].y;
                w.z += s * a4[r].z; w.w += s * a4[r].w;
            }
            ushort4 ov;
            ov.x = f2bf(w.x); ov.y = f2bf(w.y); ov.z = f2bf(w.z); ov.w = f2bf(w.w);
            ((ushort4*)(Wb + (size_t)o * DIM))[tid] = ov;
        }
    }
}

// ---------------- Kernel 2: bf16 MFMA GEMM, C = Xb * Wb^T + bias ----------------
// 128x128 / 4-wave / ring-2(BK=32, 32KB LDS) / counted vmcnt(4) / 4 blocks/CU.
// Register shape proven no-spill under (256,4) in round 1: acc[4][4]=64 AGPR,
// af[4]+bf[4]=32 VGPR, addressing ~20 -> ~116 < 128 cap. r7's spill was
// acc[8][4]=128 vs the same cap -- never again at 8 waves.
// Per quad q: STAGE(q+1) [4 loads] -> vmcnt(4) [tile q's loads landed; q+1's
// stay in flight, counted never 0 mid-loop] -> barrier [publish] -> 16 MFMA
// (setprio) -> barrier [slot q&1 reads done; STAGE(q+2) may overwrite].
// Cross-block overlap (4 independent blocks/CU) hides the per-block stalls.
__global__ __launch_bounds__(256, 4)
void gemm_bt(const unsigned short* __restrict__ Xb,
             const unsigned short* __restrict__ Wb,
             const float* __restrict__ bias,
             float* __restrict__ out) {
    __shared__ __align__(16) unsigned short S[2 * SLOT_H];   // 32 KB ring

    const int tid  = threadIdx.x;
    const int wave = tid >> 6;       // 0..3
    const int lane = tid & 63;
    const int l15  = lane & 15;
    const int lq   = lane >> 4;      // 0..3
    const int wr   = wave >> 1;      // M half 0..1 (64 rows)
    const int wc   = wave & 1;       // N half 0..1 (64 cols)

    // XCD map: grid 1536 = 8 XCDs x 192. Within an XCD, groups of 48 blocks
    // = 8bm x 6bn (A 2 MB + B 1.5 MB -> L2-fits both operands). Bijective.
    const int bid = blockIdx.x;
    const int xcd = bid & 7;
    const int s   = bid >> 3;        // 0..191
    const int g   = s / 48;          // 0..3
    const int r48 = s % 48;
    const int bm  = xcd * 8 + r48 / 6;   // 0..63
    const int bn  = g * 6 + r48 % 6;     // 0..23

    // Staging: per K-tile 16 chunks of 1 KB (A 8 + B 8). Chunk = 16 rows x
    // 32 k; lane l holds row l15, k-cols lq*8..+8 (16B). Wave w stages A
    // chunks {2w,2w+1} and B chunks {2w,2w+1} -> 4 gload_lds/wave/quad.
    // LDS chunk c = wave-uniform base + lane*16B (linear DMA order,
    // conflict-free for ds_read_b128 fragments -- verified rounds 0-6).
    const unsigned short* aptr[2];
    const unsigned short* bptr[2];
    int aoff[2], boff[2];            // chunk bases (halves) within a slot
    #pragma unroll
    for (int u = 0; u < 2; ++u) {
        const int c   = wave * 2 + u;            // 0..7
        const int row = c * 16 + l15;            // 0..127
        const int col = lq << 3;                 // 0..24
        aptr[u] = Xb + (size_t)(bm * BM + row) * K_TOT + col;
        bptr[u] = Wb + (size_t)(bn * BN + row) * K_TOT + col;
        aoff[u] = c * 512;                       // A region: halves [0, 4096)
        boff[u] = 4096 + c * 512;                // B region: halves [4096, 8192)
    }

    #define STAGE(q)                                                         \
    {                                                                        \
        unsigned short* sl = &S[((q) & 1) * SLOT_H];                         \
        const int kk = (q) * BK;                                             \
        gload_lds16(aptr[0] + kk, sl + aoff[0]);                             \
        gload_lds16(aptr[1] + kk, sl + aoff[1]);                             \
        gload_lds16(bptr[0] + kk, sl + boff[0]);                             \
        gload_lds16(bptr[1] + kk, sl + boff[1]);                             \
    }

    f4v acc[4][4] = {};

    #define COMPUTE(q)                                                       \
    {                                                                        \
        const s8v* P = (const s8v*)S + ((q) & 1) * SLOT_V;                   \
        s8v af[4], bf[4];                                                    \
        _Pragma("unroll")                                                    \
        for (int i = 0; i < 4; ++i) {                                        \
            af[i] = P[(wr * 4 + i) * 64 + lane];                             \
            bf[i] = P[B_OFF_V + (wc * 4 + i) * 64 + lane];                   \
        }                                                                    \
        __builtin_amdgcn_s_setprio(1);                                       \
        _Pragma("unroll")                                                    \
        for (int i = 0; i < 4; ++i)                                          \
            _Pragma("unroll")                                                \
            for (int j = 0; j < 4; ++j)                                      \
                acc[i][j] = __builtin_amdgcn_mfma_f32_16x16x32_bf16(         \
                    af[i], bf[j], acc[i][j], 0, 0, 0);                       \
        __builtin_amdgcn_s_setprio(0);                                       \
    }

    #define PUBSYNC(n)                                                       \
    {                                                                        \
        __builtin_amdgcn_sched_barrier(0);                                   \
        asm volatile("s_waitcnt vmcnt(" #n ")" ::: "memory");                 \
        __builtin_amdgcn_s_barrier();                                        \
        __builtin_amdgcn_sched_barrier(0);                                   \
    }
    #define ENDSYNC()                                                        \
    {                                                                        \
        __builtin_amdgcn_sched_barrier(0);                                   \
        __builtin_amdgcn_s_barrier();                                        \
        __builtin_amdgcn_sched_barrier(0);                                   \
    }

    // Prologue: tile 0 in flight.
    STAGE(0);

    #pragma unroll 2
    for (int q = 0; q < NT; ++q) {
        if (q + 1 < NT) {
            STAGE(q + 1);      // slot (q+1)&1, freed by the ENDSYNC of q-1
            PUBSYNC(4);        // tile q landed; q+1's 4 loads stay in flight
        } else {
            PUBSYNC(0);        // last tile: drain
        }
        COMPUTE(q);
        if (q + 1 < NT) ENDSYNC();   // slot q&1 reads done before STAGE(q+2)
    }
    #undef STAGE
    #undef COMPUTE
    #undef PUBSYNC
    #undef ENDSYNC

    // Epilogue: C/D layout col = lane&15, row = (lane>>4)*4 + reg  [m89]
    const int col_base = bn * BN + wc * 64;
    const int row_base = bm * BM + wr * 64 + lq * 4;
    #pragma unroll
    for (int j = 0; j < 4; ++j) {
        const int col = col_base + j * 16 + l15;
        const float bv = bias[col];
        #pragma unroll
        for (int i = 0; i < 4; ++i) {
            const int row = row_base + i * 16;
            #pragma unroll
            for (int r = 0; r < 4; ++r)
                out[(size_t)(row + r) * N_TOT + col] = acc[i][j][r] + bv;
        }
    }
}

extern "C" void kernel_launch(void* const* d_in, const int* in_sizes, int n_in,
                              void* d_out, int out_size, void* d_ws, size_t ws_size,
                              hipStream_t stream) {
    const float* x     = (const float*)d_in[0];   // [2,4096,1024]
    const float* W     = (const float*)d_in[1];   // [3072,1024]
    const float* b     = (const float*)d_in[2];   // [3072]
    const float* Aq    = (const float*)d_in[3];
    const float* Bq    = (const float*)d_in[4];
    const float* Ak    = (const float*)d_in[5];
    const float* Bk    = (const float*)d_in[6];
    const float* Av    = (const float*)d_in[7];
    const float* Bv    = (const float*)d_in[8];
    const float* alpha = (const float*)d_in[9];
    float* out = (float*)d_out;

    unsigned short* xb = (unsigned short*)d_ws;                                      // 16 MB
    unsigned short* Wb = (unsigned short*)((char*)d_ws + (size_t)M_TOT * K_TOT * 2); // +6 MB

    prep<<<2048 + 192, 256, 0, stream>>>((const float4*)x, (ushort4*)xb,
                                         W, Aq, Bq, Ak, Bk, Av, Bv, alpha, Wb);

    // 64 M-tiles x 24 N-tiles = 1536 blocks, target 4 blocks/CU co-resident
    gemm_bt<<<(M_TOT / BM) * (N_TOT / BN), 256, 0, stream>>>(xb, Wb, b, out);
}

// Round 9
// 226.761 us; speedup vs baseline: 3.2531x; 1.0581x over previous
//
#include <hip/hip_runtime.h>
#include <stdint.h>

// Problem constants
#define DIM    1024
#define RANK   16
#define M_TOT  8192          // 2*4096 rows of x
#define N_TOT  3072          // 3*DIM output features
#define K_TOT  1024

// GEMM tiling: block = 256x256, BK=32, 8 waves (2M x 4N), wave tile 128x64.
// r6 geometry (best so far, 596 TF) + FINE PHASE INTERLEAVE (the 2ph->8ph
// regime gate): each K-tile = 2 phases of {ds_reads + 2 gloads + barrier +
// lgkm0 + 16 MFMA + barrier}. Chunked LDS layout already bank-conflict-free
// (SQ_LDS_BANK_CONFLICT=0 all session) = T2 satisfied; this adds T3 (phase
// interleave), activating T5 (setprio) per m218b.
#define BM 256
#define BN 256
#define BK 32
#define NT (K_TOT / BK)      // 32 K-tiles
// LDS ring: 4 slots x 32 KB (A 16 KB + B 16 KB) = 128 KB
#define SLOT_H   16384       // halves per slot
#define SLOT_V   2048        // s8v per slot
#define B_OFF_V  1024        // B region offset within slot (s8v)

typedef __attribute__((ext_vector_type(8))) short  s8v;   // 8 x bf16 (raw bits)
typedef __attribute__((ext_vector_type(4))) float  f4v;   // MFMA acc

__device__ __forceinline__ unsigned short f2bf(float f) {
    union { float f; unsigned int u; } v; v.f = f;
    unsigned int u = v.u;
    u += 0x7FFFu + ((u >> 16) & 1u);   // round-to-nearest-even
    return (unsigned short)(u >> 16);
}

// Async global->LDS DMA, 16 B/lane. LDS dest is wave-uniform base + lane*16;
// global src carries the fragment swizzle (m173 pattern).
__device__ __forceinline__ void gload_lds16(const unsigned short* g,
                                            unsigned short* l) {
    __builtin_amdgcn_global_load_lds(
        (const __attribute__((address_space(1))) void*)g,
        (__attribute__((address_space(3))) void*)l,
        16, 0, 0);
}

// ---------------- Kernel 1: fused prep (unchanged from round 3) ----------------
__global__ __launch_bounds__(256)
void prep(const float4* __restrict__ x, ushort4* __restrict__ xb,
          const float* __restrict__ W,
          const float* __restrict__ Aq, const float* __restrict__ Bq,
          const float* __restrict__ Ak, const float* __restrict__ Bk,
          const float* __restrict__ Av, const float* __restrict__ Bv,
          const float* __restrict__ alpha_p,
          unsigned short* __restrict__ Wb) {
    const int tid = threadIdx.x;
    if (blockIdx.x < 2048) {
        int i = blockIdx.x * 256 + tid;          // 2048*256*4 = 2097152 exact
        #pragma unroll
        for (int k = 0; k < 4; ++k) {
            float4 v = x[i];
            ushort4 o;
            o.x = f2bf(v.x); o.y = f2bf(v.y); o.z = f2bf(v.z); o.w = f2bf(v.w);
            xb[i] = o;
            i += 2048 * 256;
        }
    } else {
        const int bid2 = blockIdx.x - 2048;      // 0..191
        const int sel  = bid2 >> 6;              // 0=q 1=k 2=v
        const int rb   = bid2 & 63;              // rows rb*16..+16
        const float* Am = (sel == 0) ? Aq : (sel == 1) ? Ak : Av;  // [RANK, DIM]
        const float* Bm = (sel == 0) ? Bq : (sel == 1) ? Bk : Bv;  // [DIM, RANK]

        __shared__ float sb[16][RANK];
        {
            const int row = rb * 16 + (tid >> 4);
            sb[tid >> 4][tid & 15] = alpha_p[0] * Bm[row * RANK + (tid & 15)];
        }
        __syncthreads();

        float4 a4[RANK];                          // A column-slice, 64 VGPRs
        #pragma unroll
        for (int r = 0; r < RANK; ++r)
            a4[r] = ((const float4*)(Am + r * DIM))[tid];

        #pragma unroll
        for (int row = 0; row < 16; ++row) {
            const int o = sel * 1024 + rb * 16 + row;
            float4 w = ((const float4*)(W + (size_t)o * DIM))[tid];
            #pragma unroll
            for (int r = 0; r < RANK; ++r) {
                const float s = sb[row][r];
                w.x += s * a4[r].x; w.y += s * a4[r].y;
                w.z += s * a4[r].z; w.w += s * a4[r].w;
            }
            ushort4 ov;
            ov.x = f2bf(w.x); ov.y = f2bf(w.y); ov.z = f2bf(w.z); ov.w = f2bf(w.w);
            ((ushort4*)(Wb + (size_t)o * DIM))[tid] = ov;
        }
    }
}

// ---------------- Kernel 2: bf16 MFMA GEMM, C = Xb * Wb^T + bias ----------------
// Ring-4, fine-phase schedule. Per K-tile q (2 phases):
//  ph0: read bf[0..3] + af[0..3] (8 ds_read_b128); issue 2 A-gloads of tile
//       q+3 -> slot (q+3)&3 (freed at tile q-1's end-barrier); s_barrier;
//       lgkmcnt(0)+sched_barrier; setprio(1); 16 MFMA (rows 0-3 x cols 0-3);
//       setprio(0); s_barrier.
//  ph1: read af[4..7] (4 ds); issue 2 B-gloads of tile q+3; s_barrier;
//       lgkm0+SB; setprio; 16 MFMA (rows 4-7); setprio(0);
//       [fenced: vmcnt(N) counted -> s_barrier]  (tile q+1 resident for next
//       tile; q+2,q+3's 8 loads stay in flight -- never 0 until tail).
__global__ __launch_bounds__(512, 1)
void gemm_bt(const unsigned short* __restrict__ Xb,
             const unsigned short* __restrict__ Wb,
             const float* __restrict__ bias,
             float* __restrict__ out) {
    __shared__ __align__(16) unsigned short S[4 * SLOT_H];   // 128 KB ring

    const int tid  = threadIdx.x;
    const int wave = tid >> 6;       // 0..7
    const int lane = tid & 63;
    const int l15  = lane & 15;
    const int lq   = lane >> 4;      // 0..3
    const int wr   = wave >> 2;      // M half    0..1 (128 rows)
    const int wc   = wave & 3;       // N quarter 0..3 (64 cols)

    // XCD map (r5/r6-proven): per XCD a 4bm x 12bn chunk; A-stripe 2 MB
    // L2-resident, B streams via L3. Bijective for 384 = 8 x 48.
    const int bid = blockIdx.x;
    const int xcd = bid & 7;
    const int s   = bid >> 3;        // 0..47
    const int bm  = xcd * 4 + s / 12;
    const int bn  = s % 12;

    // Staging: per K-tile 16 A-chunks + 16 B-chunks of 1 KB. Chunk c =
    // 16 rows x 32 k; lane l: row l15, k-cols lq*8..+8 (16 B). Wave w owns
    // A chunks {2w,2w+1}, B chunks {2w,2w+1} -> 4 gloads/wave/tile.
    // LDS chunk c = wave-uniform base + lane*16B (linear DMA order; this
    // fragment-major layout has measured 0 bank conflicts all session).
    const unsigned short* aptr[2];
    const unsigned short* bptr[2];
    int aoff[2], boff[2];            // chunk bases (halves) within a slot
    #pragma unroll
    for (int u = 0; u < 2; ++u) {
        const int c   = wave * 2 + u;            // 0..15
        const int row = c * 16 + l15;            // 0..255
        const int col = lq << 3;                 // 0..24
        aptr[u] = Xb + (size_t)(bm * BM + row) * K_TOT + col;
        bptr[u] = Wb + (size_t)(bn * BN + row) * K_TOT + col;
        aoff[u] = c * 512;                       // A region: halves [0, 8192)
        boff[u] = 8192 + c * 512;                // B region: halves [8192,16384)
    }

    #define STAGE_A(q)                                                       \
    {                                                                        \
        unsigned short* sl = &S[((q) & 3) * SLOT_H];                         \
        const int kk = (q) * BK;                                             \
        gload_lds16(aptr[0] + kk, sl + aoff[0]);                             \
        gload_lds16(aptr[1] + kk, sl + aoff[1]);                             \
    }
    #define STAGE_B(q)                                                       \
    {                                                                        \
        unsigned short* sl = &S[((q) & 3) * SLOT_H];                         \
        const int kk = (q) * BK;                                             \
        gload_lds16(bptr[0] + kk, sl + boff[0]);                             \
        gload_lds16(bptr[1] + kk, sl + boff[1]);                             \
    }

    f4v acc[8][4] = {};

    // One K-tile, fine-phased. DOST: stage tile q+3. WN: end-of-tile vmcnt
    // immediate (8 = tiles q+2,q+3 in flight). LAST: skip trailing sync.
    #define TILE(q, DOST, WN, LAST)                                          \
    {                                                                        \
        const s8v* PA = (const s8v*)S + ((q) & 3) * SLOT_V;                  \
        const s8v* PB = PA + B_OFF_V;                                        \
        s8v af[4], bf[4];                                                    \
        /* ---- phase 0 ---- */                                              \
        _Pragma("unroll")                                                    \
        for (int j = 0; j < 4; ++j) bf[j] = PB[(wc * 4 + j) * 64 + lane];    \
        _Pragma("unroll")                                                    \
        for (int i = 0; i < 4; ++i) af[i] = PA[(wr * 8 + i) * 64 + lane];    \
        if (DOST) STAGE_A((q) + 3);                                          \
        __builtin_amdgcn_s_barrier();                                        \
        asm volatile("s_waitcnt lgkmcnt(0)" ::: "memory");                   \
        __builtin_amdgcn_sched_barrier(0);                                   \
        __builtin_amdgcn_s_setprio(1);                                       \
        _Pragma("unroll")                                                    \
        for (int i = 0; i < 4; ++i)                                          \
            _Pragma("unroll")                                                \
            for (int j = 0; j < 4; ++j)                                      \
                acc[i][j] = __builtin_amdgcn_mfma_f32_16x16x32_bf16(         \
                    af[i], bf[j], acc[i][j], 0, 0, 0);                       \
        __builtin_amdgcn_s_setprio(0);                                       \
        __builtin_amdgcn_s_barrier();                                        \
        /* ---- phase 1 ---- */                                              \
        _Pragma("unroll")                                                    \
        for (int i = 0; i < 4; ++i) af[i] = PA[(wr * 8 + 4 + i) * 64 + lane];\
        if (DOST) STAGE_B((q) + 3);                                          \
        __builtin_amdgcn_s_barrier();                                        \
        asm volatile("s_waitcnt lgkmcnt(0)" ::: "memory");                   \
        __builtin_amdgcn_sched_barrier(0);                                   \
        __builtin_amdgcn_s_setprio(1);                                       \
        _Pragma("unroll")                                                    \
        for (int i = 0; i < 4; ++i)                                          \
            _Pragma("unroll")                                                \
            for (int j = 0; j < 4; ++j)                                      \
                acc[4 + i][j] = __builtin_amdgcn_mfma_f32_16x16x32_bf16(     \
                    af[i], bf[j], acc[4 + i][j], 0, 0, 0);                   \
        __builtin_amdgcn_s_setprio(0);                                       \
        if (!(LAST)) {                                                       \
            __builtin_amdgcn_sched_barrier(0);                               \
            asm volatile("s_waitcnt vmcnt(" #WN ")" ::: "memory");           \
            __builtin_amdgcn_s_barrier();                                    \
            __builtin_amdgcn_sched_barrier(0);                               \
        }                                                                    \
    }

    // Prologue: tiles 0,1,2 in flight (12 loads/wave); tile 0 resident after
    // vmcnt(8); tiles 1,2 (8 loads) stay in flight.
    STAGE_A(0); STAGE_B(0);
    STAGE_A(1); STAGE_B(1);
    STAGE_A(2); STAGE_B(2);
    asm volatile("s_waitcnt vmcnt(8)" ::: "memory");
    __builtin_amdgcn_sched_barrier(0);
    __builtin_amdgcn_s_barrier();
    __builtin_amdgcn_sched_barrier(0);

    // Main: q = 0..27 (28 iters, unroll 4 -> ring indices static), stages
    // tiles 3..30. Invariant entering tile q: tile q resident+published;
    // q+1, q+2 in flight (8 loads).
    #pragma unroll 4
    for (int q = 0; q < NT - 4; ++q) {
        TILE(q, true, 8, false);
    }
    // Peeled tail: q=28 stages tile 31; then drain.
    TILE(NT - 4, true,  8, false);   // q=28: stage 31; wait -> tile 29 resident
    TILE(NT - 3, false, 4, false);   // q=29: wait -> tile 30 resident, 31 in flight
    TILE(NT - 2, false, 0, false);   // q=30: drain -> tile 31 resident
    TILE(NT - 1, false, 0, true);    // q=31: compute, no trailing sync
    #undef TILE
    #undef STAGE_A
    #undef STAGE_B

    // Epilogue: C/D layout col = lane&15, row = (lane>>4)*4 + reg  [m89]
    const int col_base = bn * BN + wc * 64;
    const int row_base = bm * BM + wr * 128 + lq * 4;
    #pragma unroll
    for (int j = 0; j < 4; ++j) {
        const int col = col_base + j * 16 + l15;
        const float bv = bias[col];
        #pragma unroll
        for (int i = 0; i < 8; ++i) {
            const int row = row_base + i * 16;
            #pragma unroll
            for (int r = 0; r < 4; ++r)
                out[(size_t)(row + r) * N_TOT + col] = acc[i][j][r] + bv;
        }
    }
}

extern "C" void kernel_launch(void* const* d_in, const int* in_sizes, int n_in,
                              void* d_out, int out_size, void* d_ws, size_t ws_size,
                              hipStream_t stream) {
    const float* x     = (const float*)d_in[0];   // [2,4096,1024]
    const float* W     = (const float*)d_in[1];   // [3072,1024]
    const float* b     = (const float*)d_in[2];   // [3072]
    const float* Aq    = (const float*)d_in[3];
    const float* Bq    = (const float*)d_in[4];
    const float* Ak    = (const float*)d_in[5];
    const float* Bk    = (const float*)d_in[6];
    const float* Av    = (const float*)d_in[7];
    const float* Bv    = (const float*)d_in[8];
    const float* alpha = (const float*)d_in[9];
    float* out = (float*)d_out;

    unsigned short* xb = (unsigned short*)d_ws;                                      // 16 MB
    unsigned short* Wb = (unsigned short*)((char*)d_ws + (size_t)M_TOT * K_TOT * 2); // +6 MB

    prep<<<2048 + 192, 256, 0, stream>>>((const float4*)x, (ushort4*)xb,
                                         W, Aq, Bq, Ak, Bk, Av, Bv, alpha, Wb);

    // 32 M-tiles x 12 N-tiles = 384 blocks
    gemm_bt<<<(M_TOT / BM) * (N_TOT / BN), 512, 0, stream>>>(xb, Wb, b, out);
}